// Round 2
// baseline (346.636 us; speedup 1.0000x reference)
//
#include <hip/hip_runtime.h>
#include <math.h>

#define SUBS 20
#define TAPS 201
#define ENO 2000
#define INO 500
#define TDATA 20000

typedef __bf16 bf16x8 __attribute__((ext_vector_type(8)));
typedef float f32x4 __attribute__((ext_vector_type(4)));

#define WGE_STRIDE 2048
#define WGI_STRIDE 512

// workspace byte offsets (ws is ~640 MB per fill counter; 29.2 MB used)
#define WGE_OFF  0ull                    // ushort[64*2048] bf16 weights (E)
#define WGI_OFF  262144ull               // ushort[64*512]  bf16 weights (I)
#define KERN_OFF 327680ull               // float[40*201]   synapse kernels
#define INE_OFF  360448ull               // float[60*20000] E partial chunk0
#define INI_OFF  (INE_OFF + 4800000ull)  // float[60*20000] I (full K)
#define P1_OFF   (INI_OFF + 4800000ull)  // float[60*20000] E partial chunk1
#define P2_OFF   (P1_OFF  + 4800000ull)  // float[60*20000] E partial chunk2
#define P3_OFF   (P2_OFF  + 4800000ull)  // float[60*20000] E partial chunk3
#define SYN_OFF  (P3_OFF  + 4800000ull)  // float[60*20000] syn_in (no alias)

__device__ __forceinline__ unsigned short f2bf(float f) {
  union { float f; unsigned int u; } c; c.f = f;
  unsigned int u = c.u;
  return (unsigned short)((u + 0x7FFFu + ((u >> 16) & 1u)) >> 16);  // RTNE
}

__device__ __forceinline__ float fast_tanh(float x) {
  const float ax = fabsf(x);
  const float e  = __expf(2.f * ax);     // e=inf -> t=1 (saturation) is exact
  const float t  = 1.f - 2.f / (e + 1.f);
  return copysignf(t, x);
}

// ---------------------------------------------------------------------------
// K1: per-column prep (theta, hard/soft/softb) + kern filters + weight pads
// ---------------------------------------------------------------------------
__global__ __launch_bounds__(256) void prep_kernel(
    const float* __restrict__ u, const float* __restrict__ v,
    const float* __restrict__ C_log, const float* __restrict__ W_syn,
    const float* __restrict__ Tau_syn, const float* __restrict__ Delta_syn,
    float* __restrict__ out,
    unsigned short* __restrict__ wge, unsigned short* __restrict__ wgi,
    float* __restrict__ kern)
{
  if (blockIdx.x < 10) {
    const int n = blockIdx.x * 256 + threadIdx.x;
    if (n >= 2500) return;
    float x[SUBS], theta[SUBS], rebar[SUBS];
    float mx = -1e30f;
#pragma unroll
    for (int s = 0; s < SUBS; ++s) { x[s] = C_log[s*2500 + n]; mx = fmaxf(mx, x[s]); }
    float sum = 0.f;
#pragma unroll
    for (int s = 0; s < SUBS; ++s) { theta[s] = __expf(x[s] - mx); sum += theta[s]; }
    const float inv = 1.f / sum;
    int idx = 0; float best = -1e30f;
#pragma unroll
    for (int s = 0; s < SUBS; ++s) {
      theta[s] *= inv;
      out[60000 + s*2500 + n] = theta[s];
      const float uu = u[s*2500 + n];
      const float r = __logf(theta[s]) - __logf(-__logf(uu));
      rebar[s] = r;
      if (r > best) { best = r; idx = s; }   // first-wins strict >
    }
    const float lvk = __logf(v[idx*2500 + n]);
#pragma unroll
    for (int s = 0; s < SUBS; ++s) {
      const float hz = (s == idx) ? 1.f : 0.f;
      const float sz = 1.f / (1.f + __expf(-2.f * rebar[s])) + 1e-9f;
      const float vv = v[s*2500 + n];
      const float zb = (s == idx) ? (-__logf(-__logf(vv)))
                                  : (-__logf(-__logf(vv) / theta[s] - lvk));
      const float szb = 1.f / (1.f + __expf(-2.f * zb)) + 1e-9f;
      out[110000 + s*2500 + n] = hz;
      out[160000 + s*2500 + n] = sz;
      out[210000 + s*2500 + n] = szb;
      if (n < ENO) {
        wge[(s     )*WGE_STRIDE + n] = f2bf(hz);
        wge[(20 + s)*WGE_STRIDE + n] = f2bf(sz);
        wge[(40 + s)*WGE_STRIDE + n] = f2bf(szb);
      } else {
        const int k = n - ENO;
        wgi[(s     )*WGI_STRIDE + k] = f2bf(hz);
        wgi[(20 + s)*WGI_STRIDE + k] = f2bf(sz);
        wgi[(40 + s)*WGI_STRIDE + k] = f2bf(szb);
      }
    }
  } else {
    const int tid = threadIdx.x;
    for (int i = tid; i < 40*TAPS; i += 256) {
      const int ch = i / TAPS, m = i - ch*TAPS;
      const float dl  = __expf(Delta_syn[ch]);
      const float tau = __expf(Tau_syn[ch]);
      const float t  = fmaxf((float)m - dl, 0.f);
      const float tt = t / tau;
      kern[i] = tt * __expf(-tt) * W_syn[ch];
    }
    // zero the padded weight regions (ws is poisoned 0xAA every launch)
    for (int i = tid; i < 4*2048; i += 256) wge[(60 + (i >> 11))*WGE_STRIDE + (i & 2047)] = 0;
    for (int i = tid; i < 60*48;  i += 256) wge[(i / 48)*WGE_STRIDE + 2000 + (i % 48)] = 0;
    for (int i = tid; i < 4*512;  i += 256) wgi[(60 + (i >> 9))*WGI_STRIDE + (i & 511)] = 0;
    for (int i = tid; i < 60*12;  i += 256) wgi[(i / 12)*WGI_STRIDE + 500 + (i % 12)] = 0;
  }
}

// ---------------------------------------------------------------------------
// K2: bf16 MFMA GEMM, fragment-direct from global. NO LDS, NO barriers.
//     Each wave independently owns 16 t-rows x 64 channels. A fragments are
//     loaded per-lane from S (fp32, 2x float4 -> cast bf16x8); B fragments
//     are 16B contiguous bf16 in the padded weight buffers (L2-resident).
//     With zero __syncthreads the compiler pipelines the 96 loads/wave with
//     counted vmcnt waits; latency is hidden by ILP + ~16 waves/CU TLP.
//     grid = (313, 5); y: 0..3 = E k-quarters -> {in_e,P1,P2,P3}; 4 = I full.
//     K-tail: 4-granular address clamp (in-bounds, 16B-aligned since K%4==0);
//     misplaced A values only meet zero-padded B columns.
// ---------------------------------------------------------------------------
__global__ __launch_bounds__(256) void gemm_kernel(
    const float* __restrict__ S_e, const float* __restrict__ S_i,
    const unsigned short* __restrict__ wge, const unsigned short* __restrict__ wgi,
    float* __restrict__ in_e, float* __restrict__ in_i,
    float* __restrict__ P1, float* __restrict__ P2, float* __restrict__ P3)
{
  const int tid  = threadIdx.x;
  const int wave = tid >> 6;
  const int lane = tid & 63;
  const int m16  = lane & 15;
  const int quad = lane >> 4;
  const int t0   = blockIdx.x * 64;
  const int cy   = blockIdx.y;
  const bool isE = (cy < 4);

  const float* S = isE ? S_e : S_i;
  const unsigned short* Wg = isE ? wge : wgi;
  float* outp = (cy == 0) ? in_e : (cy == 1) ? P1 : (cy == 2) ? P2
              : (cy == 3) ? P3   : in_i;
  const int K       = isE ? ENO : INO;
  const int Wstride = isE ? WGE_STRIDE : WGI_STRIDE;
  const int k_base  = isE ? cy * 512 : 0;

  // this lane's A row (MFMA A frag: row = lane&15 within the wave's 16 rows)
  const int tA = t0 + wave*16 + m16;
  const float* Arow = S + (size_t)((tA < TDATA) ? tA : TDATA - 1) * K;
  // this lane's B rows (frag b_j: channel row = j*16 + (lane&15))
  const unsigned short* B0 = Wg + (size_t)(m16     ) * Wstride;
  const unsigned short* B1 = Wg + (size_t)(m16 + 16) * Wstride;
  const unsigned short* B2 = Wg + (size_t)(m16 + 32) * Wstride;
  const unsigned short* B3 = Wg + (size_t)(m16 + 48) * Wstride;

  f32x4 acc0 = {0.f,0.f,0.f,0.f};
  f32x4 acc1 = acc0, acc2 = acc0, acc3 = acc0;

#pragma unroll
  for (int st = 0; st < 8; ++st) {
#pragma unroll
    for (int h = 0; h < 2; ++h) {
      const int kh = k_base + st*64 + h*32 + quad*8;   // this lane's k for frag
      // A: 8 fp32 -> bf16x8, 4-granular clamped at the K tail
      const int c0 = (kh + 4 <= K) ? kh     : K - 4;
      const int c1 = (kh + 8 <= K) ? kh + 4 : K - 4;
      const float4 va = *(const float4*)(Arow + c0);
      const float4 vb = *(const float4*)(Arow + c1);
      // B: 16 contiguous bytes, already bf16 (pads zeroed by prep)
      const bf16x8 b0 = *(const bf16x8*)(B0 + kh);
      const bf16x8 b1 = *(const bf16x8*)(B1 + kh);
      const bf16x8 b2 = *(const bf16x8*)(B2 + kh);
      const bf16x8 b3 = *(const bf16x8*)(B3 + kh);
      bf16x8 a;
      a[0] = (__bf16)va.x; a[1] = (__bf16)va.y;
      a[2] = (__bf16)va.z; a[3] = (__bf16)va.w;
      a[4] = (__bf16)vb.x; a[5] = (__bf16)vb.y;
      a[6] = (__bf16)vb.z; a[7] = (__bf16)vb.w;
      acc0 = __builtin_amdgcn_mfma_f32_16x16x32_bf16(a, b0, acc0, 0, 0, 0);
      acc1 = __builtin_amdgcn_mfma_f32_16x16x32_bf16(a, b1, acc1, 0, 0, 0);
      acc2 = __builtin_amdgcn_mfma_f32_16x16x32_bf16(a, b2, acc2, 0, 0, 0);
      acc3 = __builtin_amdgcn_mfma_f32_16x16x32_bf16(a, b3, acc3, 0, 0, 0);
    }
  }

  // epilogue: C/D layout col=m16 -> channel, row=quad*4+r -> t-local
  const int t = t0 + wave*16 + quad*4;
  if (t < TDATA) {
    float* o = outp + t;
    *(float4*)(o + (size_t)(     m16)*TDATA) = *(float4*)&acc0;
    *(float4*)(o + (size_t)(16 + m16)*TDATA) = *(float4*)&acc1;
    *(float4*)(o + (size_t)(32 + m16)*TDATA) = *(float4*)&acc2;
    if (m16 < 12)
      *(float4*)(o + (size_t)(48 + m16)*TDATA) = *(float4*)&acc3;
  }
}

// ---------------------------------------------------------------------------
// K3: 201-tap causal FIR per (var,s), with the split-K reduction fused into
//     the LDS staging: E window = in_e + P1 + P2 + P3, I window = in_i.
// ---------------------------------------------------------------------------
__device__ __forceinline__ int swz(int i) { return i + (i >> 5); }

__global__ __launch_bounds__(256) void conv_kernel(
    const float* __restrict__ in_e, const float* __restrict__ P1,
    const float* __restrict__ P2,  const float* __restrict__ P3,
    const float* __restrict__ in_i,
    const float* __restrict__ kern, float* __restrict__ syn)
{
  __shared__ float Ee[2320];
  __shared__ float Ei[2320];
  const int ch = blockIdx.y;            // var*20 + s
  const int t0 = blockIdx.x * 2048;
  const int s  = ch % SUBS;
  const size_t off = (size_t)ch * TDATA;
  for (int i = threadIdx.x; i < 2248; i += 256) {
    const int g = t0 - 200 + i;
    float e = 0.f, ii = 0.f;
    if (g >= 0 && g < TDATA) {
      e = in_e[off + g] + P1[off + g] + P2[off + g] + P3[off + g];
      ii = in_i[off + g];
    }
    Ee[swz(i)] = e;
    Ei[swz(i)] = ii;
  }
  __syncthreads();
  const float* ke = kern + (size_t)(s*2    ) * TAPS;
  const float* ki = kern + (size_t)(s*2 + 1) * TAPS;
  const int tb = threadIdx.x * 8;
  float acc[8] = {0.f,0.f,0.f,0.f,0.f,0.f,0.f,0.f};
  float we[8], wi[8];
#pragma unroll
  for (int j = 0; j < 8; ++j) {
    we[j] = Ee[swz(tb + 200 + j)];
    wi[j] = Ei[swz(tb + 200 + j)];
  }
#pragma unroll 8
  for (int m = 0; m < TAPS; ++m) {
    const float k0 = ke[m];
    const float k1 = ki[m];
#pragma unroll
    for (int j = 0; j < 8; ++j)
      acc[j] = fmaf(we[j], k0, fmaf(wi[j], k1, acc[j]));
    if (m < TAPS - 1) {
#pragma unroll
      for (int j = 7; j > 0; --j) { we[j] = we[j-1]; wi[j] = wi[j-1]; }
      we[0] = Ee[swz(tb + 199 - m)];
      wi[0] = Ei[swz(tb + 199 - m)];
    }
  }
  const int t = t0 + tb;
  if (t < TDATA) {
    float* o = syn + off + t;
    *(float4*)(o    ) = make_float4(acc[0], acc[1], acc[2], acc[3]);
    *(float4*)(o + 4) = make_float4(acc[4], acc[5], acc[6], acc[7]);
  }
}

// ---------------------------------------------------------------------------
// K4: tanh tree combine -> V outputs
// ---------------------------------------------------------------------------
__global__ __launch_bounds__(256) void tree_kernel(
    const float* __restrict__ syn, const float* __restrict__ W_sub,
    const float* __restrict__ V_o, float* __restrict__ out)
{
  const int t = blockIdx.x * 256 + threadIdx.x;
  const int var = blockIdx.y;
  if (t >= TDATA) return;
  const float* sp = syn + (size_t)var * SUBS * TDATA + t;
  float so[SUBS];
#pragma unroll
  for (int s = SUBS - 1; s >= 0; --s) {
    float val = sp[(size_t)s * TDATA];
    const int c1 = 2*s + 1, c2 = 2*s + 2;
    if (c1 < SUBS) val += so[c1] * W_sub[c1];
    if (c2 < SUBS) val += so[c2] * W_sub[c2];
    so[s] = fast_tanh(val);
  }
  out[(size_t)var * TDATA + t] = so[0] * W_sub[0] + V_o[0];
}

extern "C" void kernel_launch(void* const* d_in, const int* in_sizes, int n_in,
                              void* d_out, int out_size, void* d_ws, size_t ws_size,
                              hipStream_t stream) {
  const float* S_e     = (const float*)d_in[0];
  const float* S_i     = (const float*)d_in[1];
  const float* u       = (const float*)d_in[2];
  const float* v       = (const float*)d_in[3];
  const float* W_syn   = (const float*)d_in[4];
  const float* Tau_syn = (const float*)d_in[5];
  const float* Delta   = (const float*)d_in[6];
  const float* W_sub   = (const float*)d_in[7];
  const float* V_o     = (const float*)d_in[8];
  const float* C_log   = (const float*)d_in[10];   // d_in[9] = Theta, unused
  float* out = (float*)d_out;
  char* ws = (char*)d_ws;
  unsigned short* wge = (unsigned short*)(ws + WGE_OFF);
  unsigned short* wgi = (unsigned short*)(ws + WGI_OFF);
  float* kern = (float*)(ws + KERN_OFF);
  float* in_e = (float*)(ws + INE_OFF);
  float* in_i = (float*)(ws + INI_OFF);
  float* P1   = (float*)(ws + P1_OFF);
  float* P2   = (float*)(ws + P2_OFF);
  float* P3   = (float*)(ws + P3_OFF);
  float* syn  = (float*)(ws + SYN_OFF);

  prep_kernel<<<dim3(11), dim3(256), 0, stream>>>(u, v, C_log, W_syn, Tau_syn,
                                                  Delta, out, wge, wgi, kern);
  gemm_kernel<<<dim3(313, 5), dim3(256), 0, stream>>>(
      S_e, S_i, wge, wgi, in_e, in_i, P1, P2, P3);
  conv_kernel<<<dim3(10, 60), dim3(256), 0, stream>>>(in_e, P1, P2, P3, in_i,
                                                      kern, syn);
  tree_kernel<<<dim3(79, 3), dim3(256), 0, stream>>>(syn, W_sub, V_o, out);
}